// Round 9
// baseline (1897.741 us; speedup 1.0000x reference)
//
#include <hip/hip_runtime.h>
#include <math.h>
#include <stdint.h>

typedef int v4i  __attribute__((ext_vector_type(4)));
typedef int v16i __attribute__((ext_vector_type(16)));

#define NTOK 8192
#define HID  4096
#define FFND 14336

typedef const __attribute__((address_space(1))) void* gp_t;
typedef __attribute__((address_space(3))) void*       lp_t;

#define BAR()      __builtin_amdgcn_s_barrier()
#define SETPRIO(p) __builtin_amdgcn_s_setprio(p)

// ---- repack int32 weights [OUT][IN] -> int8 fragment-major tiles ----
// layout: chunk(nt, ks, r) = ((nt*(IN/16) + ks)*32 + r) * 16 bytes,
// holding w[nt*32 + r][ks*16 .. ks*16+15].  A B-fragment load is then
// base + lane*16 (lanes 0..31 = rows at ks, lanes 32..63 = rows at ks+1).
__global__ __launch_bounds__(256) void k_repack(
    const int* __restrict__ w32, int8_t* __restrict__ w8, int IN) {
  const int nt = blockIdx.y;
  const int c  = blockIdx.x * 256 + threadIdx.x;  // ks*32 + r within nt
  const int ks = c >> 5;
  const int r  = c & 31;
  const int4* s = reinterpret_cast<const int4*>(
      w32 + (size_t)(nt * 32 + r) * IN + ks * 16);
  int4 v0 = s[0], v1 = s[1], v2 = s[2], v3 = s[3];
  int4 o;
  o.x = (v0.x & 255) | ((v0.y & 255) << 8) | ((v0.z & 255) << 16) | ((v0.w & 255) << 24);
  o.y = (v1.x & 255) | ((v1.y & 255) << 8) | ((v1.z & 255) << 16) | ((v1.w & 255) << 24);
  o.z = (v2.x & 255) | ((v2.y & 255) << 8) | ((v2.z & 255) << 16) | ((v2.w & 255) << 24);
  o.w = (v3.x & 255) | ((v3.y & 255) << 8) | ((v3.z & 255) << 16) | ((v3.w & 255) << 24);
  // int4 index: nt tiles are KS*32 int4 chunks each (KS = IN/16)
  reinterpret_cast<int4*>(w8)[(size_t)nt * (IN >> 4) * 32 + c] = o;
}

// ---------------- quantize x: fp32 -> int8, 4 elems/thread ----------------
__global__ __launch_bounds__(256) void k_quant_x(
    const float* __restrict__ x, int8_t* __restrict__ q,
    const float* __restrict__ sp, int n4) {
  int i = blockIdx.x * 256 + threadIdx.x;
  if (i >= n4) return;
  float s = *sp;
  float4 v = reinterpret_cast<const float4*>(x)[i];
  int a = (int)rintf(v.x / s); a = a < -128 ? -128 : (a > 127 ? 127 : a);
  int b = (int)rintf(v.y / s); b = b < -128 ? -128 : (b > 127 ? 127 : b);
  int c = (int)rintf(v.z / s); c = c < -128 ? -128 : (c > 127 ? 127 : c);
  int d = (int)rintf(v.w / s); d = d < -128 ? -128 : (d > 127 ? 127 : d);
  reinterpret_cast<int*>(q)[i] =
      (a & 255) | ((b & 255) << 8) | ((c & 255) << 16) | ((d & 255) << 24);
}

// ---- stage one [ROWS][64B] int8 A-tile into LDS (XOR-swizzled, rule #21) ----
template <int ROWS, int NWAVES>
__device__ __forceinline__ void stage_tile(const int8_t* __restrict__ src,
                                           int ld, int8_t* lds,
                                           int wave, int lane) {
  constexpr int NSEG = ROWS / 16;
  constexpr int PER  = NSEG / NWAVES;
#pragma unroll
  for (int j = 0; j < PER; ++j) {
    const int seg  = wave * PER + j;
    const int o    = (seg << 10) + (lane << 4);
    const int row  = o >> 6;
    const int slot = (o >> 4) & 3;
    const int gs   = slot ^ ((row >> 1) & 3);
    const int8_t* g = src + (size_t)row * ld + (gs << 4);
    __builtin_amdgcn_global_load_lds((gp_t)g, (lp_t)(lds + (seg << 10)), 16, 0, 0);
  }
}

__device__ __forceinline__ v4i frag16(const int8_t* lds, int row, int sl) {
  const int s2 = sl ^ ((row >> 1) & 3);
  return *reinterpret_cast<const v4i*>(lds + (row << 6) + (s2 << 4));
}

__device__ __forceinline__ v4i gload16(const int8_t* p) {
  return *reinterpret_cast<const v4i*>(p);
}

// ------- GEMM1: q1[T,H] x {w1,w3} -> SwiGLU -> q2 int8 -------
// 512 thr / 8 waves; tile 256x128 dual. A via LDS (depth-3, 48 KiB);
// B DIRECT global->VGPR from repacked weights (reg double-buffer).
// One barrier + one counted vmcnt(2) per K-tile.
__global__ __launch_bounds__(512, 2) void k_gemm1(
    const int8_t* __restrict__ q1, const int8_t* __restrict__ w1,
    const int8_t* __restrict__ w3, int8_t* __restrict__ q2,
    const float* __restrict__ w1sp, const float* __restrict__ w3sp,
    const float* __restrict__ a1sp, const float* __restrict__ a2sp) {
  __shared__ __align__(16) int8_t As[3][256 * 64];   // 48 KiB total
  const int lane = threadIdx.x & 63;
  const int wave = threadIdx.x >> 6;   // 0..7
  const int wr = wave >> 1;            // 0..3 (M quadrant, 64 rows)
  const int wc = wave & 1;             // 0..1 (N half, 64 cols)
  const int r0 = lane & 31;
  const int mbase = blockIdx.y * 256;
  const int nbase = blockIdx.x * 128;
  const int8_t* Ap = q1 + (size_t)mbase * HID;
  constexpr int NT  = HID / 64;        // 64 K-tiles
  constexpr int KS  = HID / 16;        // k-chunks per row-tile
  // per-wave B fragment base pointers (lane-uniform): nt = nbase/32 + wc*2 + n
  const int8_t* b1b[2];
  const int8_t* b3b[2];
#pragma unroll
  for (int n = 0; n < 2; ++n) {
    const size_t nt = (size_t)(nbase >> 5) + wc * 2 + n;
    b1b[n] = w1 + nt * KS * 512 + lane * 16;
    b3b[n] = w3 + nt * KS * 512 + lane * 16;
  }

  v16i acc1[2][2], acc3[2][2];
#pragma unroll
  for (int m = 0; m < 2; ++m)
#pragma unroll
    for (int n = 0; n < 2; ++n)
#pragma unroll
      for (int r = 0; r < 16; ++r) { acc1[m][n][r] = 0; acc3[m][n][r] = 0; }

  v4i b1A[2][2], b3A[2][2], b1B[2][2], b3B[2][2];  // [n][kk] reg dbuf

  // prologue: B(0) -> bufA (8 loads), then A-stage(0), A-stage(1)
#pragma unroll
  for (int n = 0; n < 2; ++n)
#pragma unroll
    for (int kk = 0; kk < 2; ++kk) {
      b1A[n][kk] = gload16(b1b[n] + (size_t)(0 * 4 + kk * 2) * 512);
      b3A[n][kk] = gload16(b3b[n] + (size_t)(0 * 4 + kk * 2) * 512);
    }
  stage_tile<256, 8>(Ap,      HID, As[0], wave, lane);
  stage_tile<256, 8>(Ap + 64, HID, As[1], wave, lane);

  int cur = 0;
  auto step = [&](int kt, v4i (&u1)[2][2], v4i (&u3)[2][2],
                  v4i (&f1)[2][2], v4i (&f3)[2][2]) {
    if (kt < NT - 1) asm volatile("s_waitcnt vmcnt(2)" ::: "memory");
    else             asm volatile("s_waitcnt vmcnt(0)" ::: "memory");
    BAR();
    // issue B(kt+1) into fill buffer
    if (kt + 1 < NT) {
#pragma unroll
      for (int n = 0; n < 2; ++n)
#pragma unroll
        for (int kk = 0; kk < 2; ++kk) {
          f1[n][kk] = gload16(b1b[n] + (size_t)((kt + 1) * 4 + kk * 2) * 512);
          f3[n][kk] = gload16(b3b[n] + (size_t)((kt + 1) * 4 + kk * 2) * 512);
        }
    }
    // issue A-stage(kt+2)
    if (kt + 2 < NT) {
      const int nx2 = (cur >= 1) ? cur - 1 : 2;
      stage_tile<256, 8>(Ap + (kt + 2) * 64, HID, As[nx2], wave, lane);
    }
    // A fragment reads (LDS) + MFMA; compiler interleaves freely
    const int8_t* Ac = As[cur];
    v4i a[2][2];
#pragma unroll
    for (int kk = 0; kk < 2; ++kk) {
      const int sl = kk * 2 + (lane >> 5);
      a[kk][0] = frag16(Ac, wr * 64 +      r0, sl);
      a[kk][1] = frag16(Ac, wr * 64 + 32 + r0, sl);
    }
    SETPRIO(1);
#pragma unroll
    for (int kk = 0; kk < 2; ++kk)
#pragma unroll
      for (int m = 0; m < 2; ++m)
#pragma unroll
        for (int n = 0; n < 2; ++n) {
          acc1[m][n] = __builtin_amdgcn_mfma_i32_32x32x32_i8(a[kk][m], u1[n][kk], acc1[m][n], 0, 0, 0);
          acc3[m][n] = __builtin_amdgcn_mfma_i32_32x32x32_i8(a[kk][m], u3[n][kk], acc3[m][n], 0, 0, 0);
        }
    SETPRIO(0);
    cur = (cur == 2) ? 0 : cur + 1;
  };

  for (int kt = 0; kt < NT; kt += 2) {
    step(kt,     b1A, b3A, b1B, b3B);
    step(kt + 1, b1B, b3B, b1A, b3A);
  }

  const float s1 = (*a1sp) * (*w1sp);
  const float s3 = (*a1sp) * (*w3sp);
  const float ia2 = 1.f / (*a2sp);
#pragma unroll
  for (int m = 0; m < 2; ++m)
#pragma unroll
    for (int n = 0; n < 2; ++n) {
      const int colg = nbase + wc * 64 + n * 32 + r0;
#pragma unroll
      for (int r = 0; r < 16; ++r) {
        const int rowg = mbase + wr * 64 + m * 32 +
                         (r & 3) + ((r >> 2) << 3) + ((lane >> 5) << 2);
        const float g = (float)acc1[m][n][r] * s1;
        const float u = (float)acc3[m][n][r] * s3;
        const float h = g * __builtin_amdgcn_rcpf(1.f + __expf(-g)) * u;
        float t = rintf(h * ia2);
        t = fminf(fmaxf(t, -128.f), 127.f);
        q2[(size_t)rowg * FFND + colg] = (int8_t)(int)t;
      }
    }
}

// ------- GEMM2: q2[T,FFN] x w2 -> fp32 out -------
// 256 thr / 4 waves; tile 128x128. A via LDS (24 KiB, depth-3); B direct.
__global__ __launch_bounds__(256, 3) void k_gemm2(
    const int8_t* __restrict__ q2, const int8_t* __restrict__ w2,
    float* __restrict__ out,
    const float* __restrict__ w2sp, const float* __restrict__ a2sp) {
  __shared__ __align__(16) int8_t As[3][128 * 64];  // 24 KiB total
  const int lane = threadIdx.x & 63;
  const int wave = threadIdx.x >> 6;   // 0..3
  const int wr = wave >> 1, wc = wave & 1;
  const int r0 = lane & 31;
  const int mbase = blockIdx.y * 128;
  const int nbase = blockIdx.x * 128;
  const int8_t* Ap = q2 + (size_t)mbase * FFND;
  constexpr int NT = FFND / 64;        // 224
  constexpr int KS = FFND / 16;
  const int8_t* bb[2];
#pragma unroll
  for (int n = 0; n < 2; ++n) {
    const size_t nt = (size_t)(nbase >> 5) + wc * 2 + n;
    bb[n] = w2 + nt * KS * 512 + lane * 16;
  }

  v16i acc[2][2];
#pragma unroll
  for (int m = 0; m < 2; ++m)
#pragma unroll
    for (int n = 0; n < 2; ++n)
#pragma unroll
      for (int r = 0; r < 16; ++r) acc[m][n][r] = 0;

  v4i bA[2][2], bB[2][2];

#pragma unroll
  for (int n = 0; n < 2; ++n)
#pragma unroll
    for (int kk = 0; kk < 2; ++kk)
      bA[n][kk] = gload16(bb[n] + (size_t)(kk * 2) * 512);
  stage_tile<128, 4>(Ap,      FFND, As[0], wave, lane);
  stage_tile<128, 4>(Ap + 64, FFND, As[1], wave, lane);

  int cur = 0;
  auto step = [&](int kt, v4i (&u)[2][2], v4i (&f)[2][2]) {
    if (kt < NT - 1) asm volatile("s_waitcnt vmcnt(2)" ::: "memory");
    else             asm volatile("s_waitcnt vmcnt(0)" ::: "memory");
    BAR();
    if (kt + 1 < NT) {
#pragma unroll
      for (int n = 0; n < 2; ++n)
#pragma unroll
        for (int kk = 0; kk < 2; ++kk)
          f[n][kk] = gload16(bb[n] + (size_t)((kt + 1) * 4 + kk * 2) * 512);
    }
    if (kt + 2 < NT) {
      const int nx2 = (cur >= 1) ? cur - 1 : 2;
      stage_tile<128, 4>(Ap + (kt + 2) * 64, FFND, As[nx2], wave, lane);
    }
    const int8_t* Ac = As[cur];
    v4i a[2][2];
#pragma unroll
    for (int kk = 0; kk < 2; ++kk) {
      const int sl = kk * 2 + (lane >> 5);
      a[kk][0] = frag16(Ac, wr * 64 +      r0, sl);
      a[kk][1] = frag16(Ac, wr * 64 + 32 + r0, sl);
    }
    SETPRIO(1);
#pragma unroll
    for (int kk = 0; kk < 2; ++kk)
#pragma unroll
      for (int m = 0; m < 2; ++m)
#pragma unroll
        for (int n = 0; n < 2; ++n)
          acc[m][n] = __builtin_amdgcn_mfma_i32_32x32x32_i8(a[kk][m], u[n][kk], acc[m][n], 0, 0, 0);
    SETPRIO(0);
    cur = (cur == 2) ? 0 : cur + 1;
  };

  for (int kt = 0; kt < NT; kt += 2) {
    step(kt,     bA, bB);
    step(kt + 1, bB, bA);
  }

  const float s = (*a2sp) * (*w2sp);
#pragma unroll
  for (int m = 0; m < 2; ++m)
#pragma unroll
    for (int n = 0; n < 2; ++n) {
      const int colg = nbase + wc * 64 + n * 32 + r0;
#pragma unroll
      for (int r = 0; r < 16; ++r) {
        const int rowg = mbase + wr * 64 + m * 32 +
                         (r & 3) + ((r >> 2) << 3) + ((lane >> 5) << 2);
        out[(size_t)rowg * HID + colg] = (float)acc[m][n][r] * s;
      }
    }
}

extern "C" void kernel_launch(void* const* d_in, const int* in_sizes, int n_in,
                              void* d_out, int out_size, void* d_ws, size_t ws_size,
                              hipStream_t stream) {
  const float* x    = (const float*)d_in[0];
  const int*   w1i  = (const int*)d_in[1];   // int8 values stored as int32
  const int*   w3i  = (const int*)d_in[2];
  const int*   w2i  = (const int*)d_in[3];
  const float* w1s  = (const float*)d_in[4];
  const float* w3s  = (const float*)d_in[5];
  const float* w2s  = (const float*)d_in[6];
  const float* a1s  = (const float*)d_in[7];
  const float* a2s  = (const float*)d_in[8];
  float* out = (float*)d_out;

  // workspace layout
  int8_t* q1  = (int8_t*)d_ws;                         // [NTOK][HID]    33.5 MB
  int8_t* q2  = q1 + (size_t)NTOK * HID;               // [NTOK][FFND]  117.4 MB
  int8_t* w1p = q2 + (size_t)NTOK * FFND;              // repacked       58.7 MB
  int8_t* w3p = w1p + (size_t)FFND * HID;              //                58.7 MB
  int8_t* w2p = w3p + (size_t)FFND * HID;              //                58.7 MB

  // repack weights into fragment-major tiles [OUT/32][IN/16][32][16]
  k_repack<<<dim3(HID / 128, FFND / 32), 256, 0, stream>>>(w1i, w1p, HID);
  k_repack<<<dim3(HID / 128, FFND / 32), 256, 0, stream>>>(w3i, w3p, HID);
  k_repack<<<dim3(FFND / 128, HID / 32), 256, 0, stream>>>(w2i, w2p, FFND);

  const int n4 = NTOK * HID / 4;
  k_quant_x<<<n4 / 256, 256, 0, stream>>>(x, q1, a1s, n4);
  k_gemm1<<<dim3(FFND / 128, NTOK / 256), 512, 0, stream>>>(
      q1, w1p, w3p, q2, w1s, w3s, a1s, a2s);
  k_gemm2<<<dim3(HID / 128, NTOK / 128), 256, 0, stream>>>(
      q2, w2p, out, w2s, a2s);
}

// Round 10
// 1598.457 us; speedup vs baseline: 1.1872x; 1.1872x over previous
//
#include <hip/hip_runtime.h>
#include <math.h>
#include <stdint.h>

typedef int v4i  __attribute__((ext_vector_type(4)));
typedef int v16i __attribute__((ext_vector_type(16)));

#define NTOK 8192
#define HID  4096
#define FFND 14336

typedef const __attribute__((address_space(1))) void* gp_t;
typedef __attribute__((address_space(3))) void*       lp_t;

#define BAR()      __builtin_amdgcn_s_barrier()
#define SETPRIO(p) __builtin_amdgcn_s_setprio(p)
#define MEMFENCE() asm volatile("" ::: "memory")

// ------------- pack int32 weights (values in [-127,127]) -> int8 -------------
__global__ __launch_bounds__(256) void k_pack_w(
    const int* __restrict__ w32, int8_t* __restrict__ w8, int n4) {
  int i = blockIdx.x * 256 + threadIdx.x;
  if (i >= n4) return;
  int4 v = reinterpret_cast<const int4*>(w32)[i];
  reinterpret_cast<int*>(w8)[i] =
      (v.x & 255) | ((v.y & 255) << 8) | ((v.z & 255) << 16) | ((v.w & 255) << 24);
}

// ---------------- quantize x: fp32 -> int8, 4 elems/thread ----------------
__global__ __launch_bounds__(256) void k_quant_x(
    const float* __restrict__ x, int8_t* __restrict__ q,
    const float* __restrict__ sp, int n4) {
  int i = blockIdx.x * 256 + threadIdx.x;
  if (i >= n4) return;
  float s = *sp;
  float4 v = reinterpret_cast<const float4*>(x)[i];
  int a = (int)rintf(v.x / s); a = a < -128 ? -128 : (a > 127 ? 127 : a);
  int b = (int)rintf(v.y / s); b = b < -128 ? -128 : (b > 127 ? 127 : b);
  int c = (int)rintf(v.z / s); c = c < -128 ? -128 : (c > 127 ? 127 : c);
  int d = (int)rintf(v.w / s); d = d < -128 ? -128 : (d > 127 ? 127 : d);
  reinterpret_cast<int*>(q)[i] =
      (a & 255) | ((b & 255) << 8) | ((c & 255) << 16) | ((d & 255) << 24);
}

// ---- stage one [ROWS][64B] int8 tile into LDS (XOR-swizzled, rule #21) ----
template <int ROWS, int NWAVES>
__device__ __forceinline__ void stage_tile(const int8_t* __restrict__ src,
                                           int ld, int8_t* lds,
                                           int wave, int lane) {
  constexpr int NSEG = ROWS / 16;
  constexpr int PER  = NSEG / NWAVES;
#pragma unroll
  for (int j = 0; j < PER; ++j) {
    const int seg  = wave * PER + j;
    const int o    = (seg << 10) + (lane << 4);
    const int row  = o >> 6;
    const int slot = (o >> 4) & 3;
    const int gs   = slot ^ ((row >> 1) & 3);
    const int8_t* g = src + (size_t)row * ld + (gs << 4);
    __builtin_amdgcn_global_load_lds((gp_t)g, (lp_t)(lds + (seg << 10)), 16, 0, 0);
  }
}

// read one 16B MFMA fragment (row, linear k-slot) with the inverse swizzle
__device__ __forceinline__ v4i frag16(const int8_t* lds, int row, int sl) {
  const int s2 = sl ^ ((row >> 1) & 3);
  return *reinterpret_cast<const v4i*>(lds + (row << 6) + (s2 << 4));
}

// ------- GEMM1: q1[T,H] x {w1,w3}[FFN,H]^T -> SwiGLU -> q2 int8 -------
// 256 thr / 4 waves (1 wave/SIMD); block tile 256x128 dual; per-wave 128x64
// of BOTH gate and up: m=4, n=2+2 -> 16 reads : 32 MFMAs (ratio 0.5).
// acc = 16 x v16i = 256 AGPR (unified file, 1 wave/SIMD by design).
// Depth-3 LDS (96 KiB), one barrier + one counted vmcnt(8) per K-tile.
__global__ __launch_bounds__(256, 1) void k_gemm1(
    const int8_t* __restrict__ q1, const int8_t* __restrict__ w1,
    const int8_t* __restrict__ w3, int8_t* __restrict__ q2,
    const float* __restrict__ w1sp, const float* __restrict__ w3sp,
    const float* __restrict__ a1sp, const float* __restrict__ a2sp) {
  __shared__ __align__(16) int8_t As[3][256 * 64];   // 48 KiB
  __shared__ __align__(16) int8_t B1s[3][128 * 64];  // 24 KiB
  __shared__ __align__(16) int8_t B3s[3][128 * 64];  // 24 KiB
  const int lane = threadIdx.x & 63;
  const int wave = threadIdx.x >> 6;   // 0..3
  const int wr = wave >> 1;            // 0..1 (M half, 128 rows)
  const int wc = wave & 1;             // 0..1 (N half, 64 cols)
  const int r0 = lane & 31;
  const int mbase = blockIdx.y * 256;
  const int nbase = blockIdx.x * 128;
  const int8_t* Ap  = q1 + (size_t)mbase * HID;
  const int8_t* B1p = w1 + (size_t)nbase * HID;
  const int8_t* B3p = w3 + (size_t)nbase * HID;
  constexpr int NT = HID / 64;

  v16i acc1[4][2], acc3[4][2];
#pragma unroll
  for (int m = 0; m < 4; ++m)
#pragma unroll
    for (int n = 0; n < 2; ++n)
#pragma unroll
      for (int r = 0; r < 16; ++r) { acc1[m][n][r] = 0; acc3[m][n][r] = 0; }

  // prologue: stage K-tiles 0,1 (8 loads/wave/tile: A4 + B1 2 + B3 2)
#pragma unroll
  for (int t = 0; t < 2; ++t) {
    stage_tile<256, 4>(Ap  + t * 64, HID, As[t],  wave, lane);
    stage_tile<128, 4>(B1p + t * 64, HID, B1s[t], wave, lane);
    stage_tile<128, 4>(B3p + t * 64, HID, B3s[t], wave, lane);
  }

  int cur = 0;
  for (int kt = 0; kt < NT; ++kt) {
    if (kt < NT - 1) asm volatile("s_waitcnt vmcnt(8)" ::: "memory");
    else             asm volatile("s_waitcnt vmcnt(0)" ::: "memory");
    BAR();       // tile kt fully in LDS; all waves' kt-1 reads consumed
    MEMFENCE();
    const int8_t* Ac  = As[cur];
    const int8_t* B1c = B1s[cur];
    const int8_t* B3c = B3s[cur];
    // all 16 fragment reads for this K-tile
    v4i a[2][4], b1[2][2], b3[2][2];
#pragma unroll
    for (int kk = 0; kk < 2; ++kk) {
      const int sl = kk * 2 + (lane >> 5);
#pragma unroll
      for (int m = 0; m < 4; ++m)
        a[kk][m] = frag16(Ac, wr * 128 + m * 32 + r0, sl);
#pragma unroll
      for (int n = 0; n < 2; ++n) {
        b1[kk][n] = frag16(B1c, wc * 64 + n * 32 + r0, sl);
        b3[kk][n] = frag16(B3c, wc * 64 + n * 32 + r0, sl);
      }
    }
    // prefetch K-tile kt+2 (buf last read at kt-1 -> safe post-barrier)
    const int nx2 = (cur >= 1) ? cur - 1 : 2;
    if (kt + 2 < NT) {
      stage_tile<256, 4>(Ap  + (kt + 2) * 64, HID, As[nx2],  wave, lane);
      stage_tile<128, 4>(B1p + (kt + 2) * 64, HID, B1s[nx2], wave, lane);
      stage_tile<128, 4>(B3p + (kt + 2) * 64, HID, B3s[nx2], wave, lane);
    }
    // MFMA cluster: compiler interleaves pending ds_reads into the stream
    SETPRIO(1);
#pragma unroll
    for (int kk = 0; kk < 2; ++kk)
#pragma unroll
      for (int m = 0; m < 4; ++m)
#pragma unroll
        for (int n = 0; n < 2; ++n) {
          acc1[m][n] = __builtin_amdgcn_mfma_i32_32x32x32_i8(a[kk][m], b1[kk][n], acc1[m][n], 0, 0, 0);
          acc3[m][n] = __builtin_amdgcn_mfma_i32_32x32x32_i8(a[kk][m], b3[kk][n], acc3[m][n], 0, 0, 0);
        }
    SETPRIO(0);
    cur = (cur == 2) ? 0 : cur + 1;
  }

  const float s1 = (*a1sp) * (*w1sp);
  const float s3 = (*a1sp) * (*w3sp);
  const float ia2 = 1.f / (*a2sp);
#pragma unroll
  for (int m = 0; m < 4; ++m)
#pragma unroll
    for (int n = 0; n < 2; ++n) {
      const int colg = nbase + wc * 64 + n * 32 + r0;
#pragma unroll
      for (int r = 0; r < 16; ++r) {
        const int rowg = mbase + wr * 128 + m * 32 +
                         (r & 3) + ((r >> 2) << 3) + ((lane >> 5) << 2);
        const float g = (float)acc1[m][n][r] * s1;
        const float u = (float)acc3[m][n][r] * s3;
        const float h = g * __builtin_amdgcn_rcpf(1.f + __expf(-g)) * u;
        float t = rintf(h * ia2);
        t = fminf(fmaxf(t, -128.f), 127.f);
        q2[(size_t)rowg * FFND + colg] = (int8_t)(int)t;
      }
    }
}

// ------- GEMM2: q2[T,FFN] x w2[HID,FFN]^T -> fp32 out -------
// 256 thr / 4 waves (1 wave/SIMD); block 256x256; per-wave 128x128 (m=4,n=4,
// ratio 0.5, acc 256 AGPR). Depth-3 (96 KiB), vmcnt(8).
__global__ __launch_bounds__(256, 1) void k_gemm2(
    const int8_t* __restrict__ q2, const int8_t* __restrict__ w2,
    float* __restrict__ out,
    const float* __restrict__ w2sp, const float* __restrict__ a2sp) {
  __shared__ __align__(16) int8_t As[3][256 * 64];  // 48 KiB
  __shared__ __align__(16) int8_t Bs[3][256 * 64];  // 48 KiB
  const int lane = threadIdx.x & 63;
  const int wave = threadIdx.x >> 6;   // 0..3
  const int wr = wave >> 1;            // 0..1 (M half, 128 rows)
  const int wc = wave & 1;             // 0..1 (N half, 128 cols)
  const int r0 = lane & 31;
  const int mbase = blockIdx.y * 256;
  const int nbase = blockIdx.x * 256;
  const int8_t* Ap = q2 + (size_t)mbase * FFND;
  const int8_t* Bp = w2 + (size_t)nbase * FFND;
  constexpr int NT = FFND / 64;

  v16i acc[4][4];
#pragma unroll
  for (int m = 0; m < 4; ++m)
#pragma unroll
    for (int n = 0; n < 4; ++n)
#pragma unroll
      for (int r = 0; r < 16; ++r) acc[m][n][r] = 0;

#pragma unroll
  for (int t = 0; t < 2; ++t) {
    stage_tile<256, 4>(Ap + t * 64, FFND, As[t], wave, lane);
    stage_tile<256, 4>(Bp + t * 64, FFND, Bs[t], wave, lane);
  }

  int cur = 0;
  for (int kt = 0; kt < NT; ++kt) {
    if (kt < NT - 1) asm volatile("s_waitcnt vmcnt(8)" ::: "memory");
    else             asm volatile("s_waitcnt vmcnt(0)" ::: "memory");
    BAR();
    MEMFENCE();
    const int8_t* Ac = As[cur];
    const int8_t* Bc = Bs[cur];
    v4i a[2][4], b[2][4];
#pragma unroll
    for (int kk = 0; kk < 2; ++kk) {
      const int sl = kk * 2 + (lane >> 5);
#pragma unroll
      for (int m = 0; m < 4; ++m)
        a[kk][m] = frag16(Ac, wr * 128 + m * 32 + r0, sl);
#pragma unroll
      for (int n = 0; n < 4; ++n)
        b[kk][n] = frag16(Bc, wc * 128 + n * 32 + r0, sl);
    }
    const int nx2 = (cur >= 1) ? cur - 1 : 2;
    if (kt + 2 < NT) {
      stage_tile<256, 4>(Ap + (kt + 2) * 64, FFND, As[nx2], wave, lane);
      stage_tile<256, 4>(Bp + (kt + 2) * 64, FFND, Bs[nx2], wave, lane);
    }
    SETPRIO(1);
#pragma unroll
    for (int kk = 0; kk < 2; ++kk)
#pragma unroll
      for (int m = 0; m < 4; ++m)
#pragma unroll
        for (int n = 0; n < 4; ++n)
          acc[m][n] = __builtin_amdgcn_mfma_i32_32x32x32_i8(a[kk][m], b[kk][n], acc[m][n], 0, 0, 0);
    SETPRIO(0);
    cur = (cur == 2) ? 0 : cur + 1;
  }

  const float s = (*a2sp) * (*w2sp);
#pragma unroll
  for (int m = 0; m < 4; ++m)
#pragma unroll
    for (int n = 0; n < 4; ++n) {
      const int colg = nbase + wc * 128 + n * 32 + r0;
#pragma unroll
      for (int r = 0; r < 16; ++r) {
        const int rowg = mbase + wr * 128 + m * 32 +
                         (r & 3) + ((r >> 2) << 3) + ((lane >> 5) << 2);
        out[(size_t)rowg * HID + colg] = (float)acc[m][n][r] * s;
      }
    }
}

extern "C" void kernel_launch(void* const* d_in, const int* in_sizes, int n_in,
                              void* d_out, int out_size, void* d_ws, size_t ws_size,
                              hipStream_t stream) {
  const float* x    = (const float*)d_in[0];
  const int*   w1i  = (const int*)d_in[1];   // int8 values stored as int32
  const int*   w3i  = (const int*)d_in[2];
  const int*   w2i  = (const int*)d_in[3];
  const float* w1s  = (const float*)d_in[4];
  const float* w3s  = (const float*)d_in[5];
  const float* w2s  = (const float*)d_in[6];
  const float* a1s  = (const float*)d_in[7];
  const float* a2s  = (const float*)d_in[8];
  float* out = (float*)d_out;

  // workspace layout
  int8_t* q1  = (int8_t*)d_ws;                         // [NTOK][HID]    33.5 MB
  int8_t* q2  = q1 + (size_t)NTOK * HID;               // [NTOK][FFND]  117.4 MB
  int8_t* w1p = q2 + (size_t)NTOK * FFND;              // [FFN][HID]     58.7 MB
  int8_t* w3p = w1p + (size_t)FFND * HID;              //                58.7 MB
  int8_t* w2p = w3p + (size_t)FFND * HID;              // [HID][FFN]     58.7 MB

  const int wn4 = (int)((size_t)FFND * HID / 4);
  k_pack_w<<<wn4 / 256, 256, 0, stream>>>(w1i, w1p, wn4);
  k_pack_w<<<wn4 / 256, 256, 0, stream>>>(w3i, w3p, wn4);
  k_pack_w<<<wn4 / 256, 256, 0, stream>>>(w2i, w2p, wn4);

  const int n4 = NTOK * HID / 4;
  k_quant_x<<<n4 / 256, 256, 0, stream>>>(x, q1, a1s, n4);
  k_gemm1<<<dim3(FFND / 128, NTOK / 256), 256, 0, stream>>>(
      q1, w1p, w3p, q2, w1s, w3s, a1s, a2s);
  k_gemm2<<<dim3(HID / 256, NTOK / 256), 256, 0, stream>>>(
      q2, w2p, out, w2s, a2s);
}